// Round 5
// baseline (755.938 us; speedup 1.0000x reference)
//
#include <hip/hip_runtime.h>
#include <stdint.h>

// GNN layer on MI355X. Inputs f32, output f32 (per reference). Edge MLP via
// bf16 MFMA (f32 accum). Scatter-reduce over dst done via CSR sort + gather
// (no f32 atomics) when workspace permits; atomic fallback otherwise.

typedef __attribute__((ext_vector_type(8))) short short8;   // 8 bf16 = 4 VGPRs
typedef __attribute__((ext_vector_type(4))) float floatx4;  // MFMA C/D

__device__ __forceinline__ float b2f(short s) {
    union { float f; uint32_t u; } v; v.u = ((uint32_t)(uint16_t)s) << 16; return v.f;
}
__device__ __forceinline__ short f2b(float f) {
    union { float f; uint32_t u; } v; v.f = f;
    uint32_t u = v.u;
    uint32_t r = (u + 0x7fff + ((u >> 16) & 1)) >> 16;  // RNE
    return (short)r;
}

#define NEG 0.01f

// ---------------- weight canonicalization f32 -> bf16, transposed ----------
__global__ void prep_kernel(const float* __restrict__ w1, const float* __restrict__ w2,
                            const float* __restrict__ w3, const float* __restrict__ wi,
                            const float* __restrict__ wo,
                            short* __restrict__ w1t, short* __restrict__ w2t,
                            short* __restrict__ w3t, short* __restrict__ wit,
                            short* __restrict__ wot) {
    int t = blockIdx.x * 256 + threadIdx.x;  // 65536 threads
    if (t < 32768) { int k = t >> 7, n = t & 127; w1t[n * 256 + k] = f2b(w1[t]); }
    if (t < 16384) {
        int k = t >> 7, n = t & 127;
        w2t[n * 128 + k] = f2b(w2[t]);
        w3t[n * 128 + k] = f2b(w3[t]);
    }
    { int k = t >> 9, n = t & 511; wit[n * 128 + k] = f2b(wi[t]); }
    { int k = t >> 7, n = t & 127; wot[n * 512 + k] = f2b(wo[t]); }
}

// ---------------- CSR build ----------------
__global__ void csr_count_kernel(const int* __restrict__ dst, int E, int* __restrict__ cnt) {
    int e = blockIdx.x * 256 + threadIdx.x;
    if (e < E) atomicAdd(&cnt[dst[e]], 1);
}

__global__ __launch_bounds__(1024) void csr_scan_kernel(const int* __restrict__ cnt,
                                                        int N, int* __restrict__ rowptr) {
    __shared__ int part[1024];
    int t = threadIdx.x;
    int per = (N + 1023) >> 10;
    int beg = t * per;
    int end = beg + per; if (end > N) end = N; if (beg > N) beg = N;
    int s = 0;
    for (int i = beg; i < end; ++i) s += cnt[i];
    part[t] = s;
    __syncthreads();
    for (int off = 1; off < 1024; off <<= 1) {
        int v = (t >= off) ? part[t - off] : 0;
        __syncthreads();
        part[t] += v;
        __syncthreads();
    }
    int run = part[t] - s;  // exclusive prefix
    for (int i = beg; i < end; ++i) { rowptr[i] = run; run += cnt[i]; }
    if (t == 1023) rowptr[N] = part[1023];
}

__global__ void csr_scatter_kernel(const int* __restrict__ dst, int E,
                                   const int* __restrict__ rowptr,
                                   int* __restrict__ cursor, int* __restrict__ eid) {
    int e = blockIdx.x * 256 + threadIdx.x;
    if (e < E) {
        int d = dst[e];
        int p = atomicAdd(&cursor[d], 1);
        eid[rowptr[d] + p] = e;
    }
}

// ---------------- edge kernel ----------------
// 64 edges/block, 256 threads (4 waves). Wave w owns output cols [32w,32w+32).
// MODE 0: atomic scatter into num/denom.  MODE 1: write bf16 msg rows + att.
template <int MODE>
__global__ __launch_bounds__(256) void edge_kernel(
    const float* __restrict__ hV, const float* __restrict__ hE,
    const int* __restrict__ dst, int E,
    const short* __restrict__ w1t, const short* __restrict__ w2t,
    const short* __restrict__ w3t,
    const float* __restrict__ b1, const float* __restrict__ b2,
    const float* __restrict__ b3, const float* __restrict__ Av,
    float* __restrict__ num, float* __restrict__ denom,
    short* __restrict__ msg, float* __restrict__ att_g) {
    __shared__ short smA[64 * 264];   // M (bf16, stride 264), later h2 (stride 136)
    __shared__ short smH1[64 * 136];
    __shared__ float s_att[64];
    __shared__ int s_dst[64];
    __shared__ float s_part[64][4];

    const int tid = threadIdx.x;
    const int lane = tid & 63;
    const int wv = tid >> 6;
    const int e0 = blockIdx.x * 64;

    if (tid < 64) {
        int e = e0 + tid; if (e >= E) e = E - 1;
        s_dst[tid] = dst[e];
    }
    __syncthreads();

    // stage M = [h_V[dst] | h_E] (64 rows x 256), f32 -> bf16
#pragma unroll
    for (int i = 0; i < 8; ++i) {
        int c = tid + i * 256;
        int row = c >> 5;
        int off = (c & 31) * 8;
        int e = e0 + row; if (e >= E) e = E - 1;
        const float* src = (off < 128)
            ? (hV + (size_t)s_dst[row] * 128 + off)
            : (hE + (size_t)e * 128 + (off - 128));
        float4 a0 = *(const float4*)(src);
        float4 a1 = *(const float4*)(src + 4);
        short8 v;
        v[0] = f2b(a0.x); v[1] = f2b(a0.y); v[2] = f2b(a0.z); v[3] = f2b(a0.w);
        v[4] = f2b(a1.x); v[5] = f2b(a1.y); v[6] = f2b(a1.z); v[7] = f2b(a1.w);
        *(short8*)(&smA[row * 264 + off]) = v;
    }
    __syncthreads();

    // attention: att = exp(sigmoid(lrelu(m . A)))  (A read in f32)
    {
        int e = tid >> 2, p = tid & 3;
        const short* mr = &smA[e * 264 + p * 64];
        const float* ar = &Av[p * 64];
        float s = 0.f;
#pragma unroll 8
        for (int k = 0; k < 64; ++k) s += b2f(mr[k]) * ar[k];
        s_part[e][p] = s;
    }
    __syncthreads();
    if (tid < 64) {
        float x = s_part[tid][0] + s_part[tid][1] + s_part[tid][2] + s_part[tid][3];
        float z = (x >= 0.f) ? x : NEG * x;
        float a = expf(1.f / (1.f + expf(-z)));
        s_att[tid] = a;
        if (e0 + tid < E) {
            if (MODE == 0) unsafeAtomicAdd(&denom[s_dst[tid]], a);
            else att_g[e0 + tid] = a;
        }
    }
    __syncthreads();

    const int q = lane >> 4, r = lane & 15;
    const int cb = wv * 32;
    floatx4 zero = {0.f, 0.f, 0.f, 0.f};

    // ---- layer 1: h1 = lrelu(M @ w1 + b1), K=256 ----
    {
        floatx4 acc[4][2];
#pragma unroll
        for (int rt = 0; rt < 4; ++rt) { acc[rt][0] = zero; acc[rt][1] = zero; }
#pragma unroll
        for (int ks = 0; ks < 8; ++ks) {
            short8 bA = *(const short8*)(w1t + (cb + r) * 256 + ks * 32 + q * 8);
            short8 bB = *(const short8*)(w1t + (cb + 16 + r) * 256 + ks * 32 + q * 8);
#pragma unroll
            for (int rt = 0; rt < 4; ++rt) {
                short8 a = *(const short8*)(&smA[(rt * 16 + r) * 264 + ks * 32 + q * 8]);
                acc[rt][0] = __builtin_amdgcn_mfma_f32_16x16x32_bf16(a, bA, acc[rt][0], 0, 0, 0);
                acc[rt][1] = __builtin_amdgcn_mfma_f32_16x16x32_bf16(a, bB, acc[rt][1], 0, 0, 0);
            }
        }
#pragma unroll
        for (int ct = 0; ct < 2; ++ct) {
            int col = cb + ct * 16 + r;
            float bias = b1[col];
#pragma unroll
            for (int rt = 0; rt < 4; ++rt)
#pragma unroll
                for (int rr = 0; rr < 4; ++rr) {
                    int row = rt * 16 + q * 4 + rr;
                    float v = acc[rt][ct][rr] + bias;
                    v = (v >= 0.f) ? v : NEG * v;
                    smH1[row * 136 + col] = f2b(v);
                }
        }
    }
    __syncthreads();

    // ---- layer 2: h2 = lrelu(h1 @ w2 + b2), K=128; h2 -> smA region ----
    {
        floatx4 acc[4][2];
#pragma unroll
        for (int rt = 0; rt < 4; ++rt) { acc[rt][0] = zero; acc[rt][1] = zero; }
#pragma unroll
        for (int ks = 0; ks < 4; ++ks) {
            short8 bA = *(const short8*)(w2t + (cb + r) * 128 + ks * 32 + q * 8);
            short8 bB = *(const short8*)(w2t + (cb + 16 + r) * 128 + ks * 32 + q * 8);
#pragma unroll
            for (int rt = 0; rt < 4; ++rt) {
                short8 a = *(const short8*)(&smH1[(rt * 16 + r) * 136 + ks * 32 + q * 8]);
                acc[rt][0] = __builtin_amdgcn_mfma_f32_16x16x32_bf16(a, bA, acc[rt][0], 0, 0, 0);
                acc[rt][1] = __builtin_amdgcn_mfma_f32_16x16x32_bf16(a, bB, acc[rt][1], 0, 0, 0);
            }
        }
        short* smH2 = smA;  // M fully consumed
#pragma unroll
        for (int ct = 0; ct < 2; ++ct) {
            int col = cb + ct * 16 + r;
            float bias = b2[col];
#pragma unroll
            for (int rt = 0; rt < 4; ++rt)
#pragma unroll
                for (int rr = 0; rr < 4; ++rr) {
                    int row = rt * 16 + q * 4 + rr;
                    float v = acc[rt][ct][rr] + bias;
                    v = (v >= 0.f) ? v : NEG * v;
                    smH2[row * 136 + col] = f2b(v);
                }
        }
    }
    __syncthreads();

    // ---- layer 3: hm = h2 @ w3 + b3; weighted by att ----
    {
        const short* smH2 = smA;
        floatx4 acc[4][2];
#pragma unroll
        for (int rt = 0; rt < 4; ++rt) { acc[rt][0] = zero; acc[rt][1] = zero; }
#pragma unroll
        for (int ks = 0; ks < 4; ++ks) {
            short8 bA = *(const short8*)(w3t + (cb + r) * 128 + ks * 32 + q * 8);
            short8 bB = *(const short8*)(w3t + (cb + 16 + r) * 128 + ks * 32 + q * 8);
#pragma unroll
            for (int rt = 0; rt < 4; ++rt) {
                short8 a = *(const short8*)(&smH2[(rt * 16 + r) * 136 + ks * 32 + q * 8]);
                acc[rt][0] = __builtin_amdgcn_mfma_f32_16x16x32_bf16(a, bA, acc[rt][0], 0, 0, 0);
                acc[rt][1] = __builtin_amdgcn_mfma_f32_16x16x32_bf16(a, bB, acc[rt][1], 0, 0, 0);
            }
        }
        if (MODE == 0) {
#pragma unroll
            for (int ct = 0; ct < 2; ++ct) {
                int col = cb + ct * 16 + r;
                float bias = b3[col];
#pragma unroll
                for (int rt = 0; rt < 4; ++rt)
#pragma unroll
                    for (int rr = 0; rr < 4; ++rr) {
                        int row = rt * 16 + q * 4 + rr;
                        if (e0 + row < E) {
                            float v = (acc[rt][ct][rr] + bias) * s_att[row];
                            unsafeAtomicAdd(&num[(size_t)s_dst[row] * 128 + col], v);
                        }
                    }
            }
        } else {
            // stage weighted bf16 rows in LDS (smH1 is dead), then coalesced copy-out
#pragma unroll
            for (int ct = 0; ct < 2; ++ct) {
                int col = cb + ct * 16 + r;
                float bias = b3[col];
#pragma unroll
                for (int rt = 0; rt < 4; ++rt)
#pragma unroll
                    for (int rr = 0; rr < 4; ++rr) {
                        int row = rt * 16 + q * 4 + rr;
                        float v = (acc[rt][ct][rr] + bias) * s_att[row];
                        smH1[row * 136 + col] = f2b(v);
                    }
            }
            __syncthreads();
#pragma unroll
            for (int p = 0; p < 4; ++p) {
                int chunk = tid + p * 256;      // 0..1023
                int row = chunk >> 4;           // 64 rows
                int off = (chunk & 15) * 8;     // 16B chunks
                if (e0 + row < E)
                    *(int4*)(msg + (size_t)(e0 + row) * 128 + off) =
                        *(const int4*)(&smH1[row * 136 + off]);
            }
        }
    }
}

// ---------------- node LN1 (atomic-path variant) ----------------
__global__ __launch_bounds__(256) void node1_kernel(
    const float* __restrict__ hV, const float* __restrict__ num,
    const float* __restrict__ denom, const float* __restrict__ g1,
    const float* __restrict__ be1, int N, short* __restrict__ hv1b) {
    int n = blockIdx.x * 4 + (threadIdx.x >> 6);
    int lane = threadIdx.x & 63;
    if (n >= N) return;
    float d = denom[n];
    float inv = (d > 0.f) ? 1.f / (d * 30.f) : 0.f;
    size_t base = (size_t)n * 128;
    float x0 = hV[base + lane] + num[base + lane] * inv;
    float x1 = hV[base + lane + 64] + num[base + lane + 64] * inv;
    float s = x0 + x1, sq = x0 * x0 + x1 * x1;
#pragma unroll
    for (int o = 32; o > 0; o >>= 1) {
        s += __shfl_down(s, o);
        sq += __shfl_down(sq, o);
    }
    s = __shfl(s, 0); sq = __shfl(sq, 0);
    float mu = s * 0.0078125f;
    float var = sq * 0.0078125f - mu * mu;
    float rstd = rsqrtf(var + 1e-6f);
    float y0 = g1[lane] * (x0 - mu) * rstd + be1[lane];
    float y1 = g1[lane + 64] * (x1 - mu) * rstd + be1[lane + 64];
    hv1b[base + lane] = f2b(y0);
    hv1b[base + lane + 64] = f2b(y1);
}

// ---------------- node gather-reduce + LN1 (CSR path) ----------------
// 1 wave per node, 4 nodes/block. Lane handles cols 2*lane, 2*lane+1.
__global__ __launch_bounds__(256) void node1_csr_kernel(
    const float* __restrict__ hV, const short* __restrict__ msg,
    const float* __restrict__ att, const int* __restrict__ rowptr,
    const int* __restrict__ eid, const float* __restrict__ g1,
    const float* __restrict__ be1, int N, short* __restrict__ hv1b) {
    int n = blockIdx.x * 4 + (threadIdx.x >> 6);
    int lane = threadIdx.x & 63;
    if (n >= N) return;
    int beg = rowptr[n], end = rowptr[n + 1];
    float acc0 = 0.f, acc1 = 0.f, den = 0.f;
    for (int i = beg; i < end; ++i) {
        int e = eid[i];                 // wave-uniform broadcast
        uint32_t m = *(const uint32_t*)(msg + (size_t)e * 128 + lane * 2);
        float a = att[e];
        acc0 += b2f((short)(m & 0xffffu));
        acc1 += b2f((short)(m >> 16));
        den += a;
    }
    float inv = (den > 0.f) ? 1.f / (den * 30.f) : 0.f;
    size_t base = (size_t)n * 128;
    float2 h = *(const float2*)(hV + base + lane * 2);
    float x0 = h.x + acc0 * inv;
    float x1 = h.y + acc1 * inv;
    float s = x0 + x1, sq = x0 * x0 + x1 * x1;
#pragma unroll
    for (int o = 32; o > 0; o >>= 1) {
        s += __shfl_down(s, o);
        sq += __shfl_down(sq, o);
    }
    s = __shfl(s, 0); sq = __shfl(sq, 0);
    float mu = s * 0.0078125f;
    float var = sq * 0.0078125f - mu * mu;
    float rstd = rsqrtf(var + 1e-6f);
    float y0 = g1[lane * 2] * (x0 - mu) * rstd + be1[lane * 2];
    float y1 = g1[lane * 2 + 1] * (x1 - mu) * rstd + be1[lane * 2 + 1];
    uint32_t pack = (uint32_t)(uint16_t)f2b(y0) | ((uint32_t)(uint16_t)f2b(y1) << 16);
    *(uint32_t*)(hv1b + base + lane * 2) = pack;
}

// ---------------- FFN + LN2 (f32 output) ----------------
__global__ __launch_bounds__(256) void ffn_kernel(
    const short* __restrict__ hv1b,
    const short* __restrict__ wit, const short* __restrict__ wot,
    const float* __restrict__ bi, const float* __restrict__ bo,
    const float* __restrict__ g2, const float* __restrict__ be2,
    int N, float* __restrict__ out) {
    __shared__ short smX[32 * 136];
    __shared__ short smT[32 * 520];
    __shared__ float smD[32][128];
    __shared__ float smR[32][8][2];
    __shared__ float smS[32][2];

    const int tid = threadIdx.x;
    const int lane = tid & 63;
    const int wv = tid >> 6;
    const int nb = blockIdx.x * 32;

#pragma unroll
    for (int i = 0; i < 2; ++i) {
        int c = tid + i * 256;
        int row = c >> 4;
        int off = (c & 15) * 8;
        int n = nb + row; if (n >= N) n = N - 1;
        *(int4*)(&smX[row * 136 + off]) = *(const int4*)(hv1b + (size_t)n * 128 + off);
    }
    __syncthreads();

    const int q = lane >> 4, r = lane & 15;
    floatx4 zero = {0.f, 0.f, 0.f, 0.f};

    {   // T = relu(X @ wi + bi), K=128
        floatx4 acc[2][8];
#pragma unroll
        for (int ct = 0; ct < 8; ++ct) { acc[0][ct] = zero; acc[1][ct] = zero; }
        const int cb = wv * 128;
#pragma unroll
        for (int ks = 0; ks < 4; ++ks) {
            short8 a0 = *(const short8*)(&smX[r * 136 + ks * 32 + q * 8]);
            short8 a1 = *(const short8*)(&smX[(16 + r) * 136 + ks * 32 + q * 8]);
#pragma unroll
            for (int ct = 0; ct < 8; ++ct) {
                short8 b = *(const short8*)(wit + (size_t)(cb + ct * 16 + r) * 128 + ks * 32 + q * 8);
                acc[0][ct] = __builtin_amdgcn_mfma_f32_16x16x32_bf16(a0, b, acc[0][ct], 0, 0, 0);
                acc[1][ct] = __builtin_amdgcn_mfma_f32_16x16x32_bf16(a1, b, acc[1][ct], 0, 0, 0);
            }
        }
#pragma unroll
        for (int ct = 0; ct < 8; ++ct) {
            int col = cb + ct * 16 + r;
            float bias = bi[col];
#pragma unroll
            for (int rt = 0; rt < 2; ++rt)
#pragma unroll
                for (int rr = 0; rr < 4; ++rr) {
                    int row = rt * 16 + q * 4 + rr;
                    float v = acc[rt][ct][rr] + bias;
                    smT[row * 520 + col] = f2b(v > 0.f ? v : 0.f);
                }
        }
    }
    __syncthreads();

    {   // dh2 = T @ wo + bo, K=512
        floatx4 acc[2][2];
        acc[0][0] = zero; acc[0][1] = zero; acc[1][0] = zero; acc[1][1] = zero;
        const int cb = wv * 32;
#pragma unroll
        for (int ks = 0; ks < 16; ++ks) {
            short8 bA = *(const short8*)(wot + (size_t)(cb + r) * 512 + ks * 32 + q * 8);
            short8 bB = *(const short8*)(wot + (size_t)(cb + 16 + r) * 512 + ks * 32 + q * 8);
            short8 a0 = *(const short8*)(&smT[r * 520 + ks * 32 + q * 8]);
            short8 a1 = *(const short8*)(&smT[(16 + r) * 520 + ks * 32 + q * 8]);
            acc[0][0] = __builtin_amdgcn_mfma_f32_16x16x32_bf16(a0, bA, acc[0][0], 0, 0, 0);
            acc[0][1] = __builtin_amdgcn_mfma_f32_16x16x32_bf16(a0, bB, acc[0][1], 0, 0, 0);
            acc[1][0] = __builtin_amdgcn_mfma_f32_16x16x32_bf16(a1, bA, acc[1][0], 0, 0, 0);
            acc[1][1] = __builtin_amdgcn_mfma_f32_16x16x32_bf16(a1, bB, acc[1][1], 0, 0, 0);
        }
#pragma unroll
        for (int ct = 0; ct < 2; ++ct) {
            int col = cb + ct * 16 + r;
            float bias = bo[col];
#pragma unroll
            for (int rt = 0; rt < 2; ++rt)
#pragma unroll
                for (int rr = 0; rr < 4; ++rr) {
                    int row = rt * 16 + q * 4 + rr;
                    smD[row][col] = acc[rt][ct][rr] + bias;
                }
        }
    }
    __syncthreads();

    {   // LN2 over x = hv1 + dh2
        int row = tid >> 3, j = tid & 7;
        int n = nb + row;
        float s = 0.f, sq = 0.f;
#pragma unroll
        for (int c = j * 16; c < j * 16 + 16; ++c) {
            float x = (n < N ? b2f(hv1b[(size_t)n * 128 + c]) : 0.f) + smD[row][c];
            smD[row][c] = x;
            s += x; sq += x * x;
        }
        smR[row][j][0] = s; smR[row][j][1] = sq;
    }
    __syncthreads();
    if ((tid & 7) == 0) {
        int row = tid >> 3;
        float s = 0.f, sq = 0.f;
#pragma unroll
        for (int j = 0; j < 8; ++j) { s += smR[row][j][0]; sq += smR[row][j][1]; }
        float mu = s * 0.0078125f;
        float var = sq * 0.0078125f - mu * mu;
        smS[row][0] = mu;
        smS[row][1] = rsqrtf(var + 1e-6f);
    }
    __syncthreads();
    {
        int row = tid >> 3, j = tid & 7;
        int n = nb + row;
        if (n < N) {
            float mu = smS[row][0], rstd = smS[row][1];
#pragma unroll
            for (int c = j * 16; c < j * 16 + 16; ++c) {
                float y = g2[c] * (smD[row][c] - mu) * rstd + be2[c];
                out[(size_t)n * 128 + c] = y;   // f32 output
            }
        }
    }
}

static inline size_t align256(size_t x) { return (x + 255) & ~(size_t)255; }

extern "C" void kernel_launch(void* const* d_in, const int* in_sizes, int n_in,
                              void* d_out, int out_size, void* d_ws, size_t ws_size,
                              hipStream_t stream) {
    const float* hV  = (const float*)d_in[0];
    const float* hE  = (const float*)d_in[1];
    const float* w1  = (const float*)d_in[2];
    const float* b1  = (const float*)d_in[3];
    const float* w2  = (const float*)d_in[4];
    const float* b2  = (const float*)d_in[5];
    const float* w3  = (const float*)d_in[6];
    const float* b3  = (const float*)d_in[7];
    const float* Av  = (const float*)d_in[8];
    const float* wi  = (const float*)d_in[9];
    const float* bi  = (const float*)d_in[10];
    const float* wo  = (const float*)d_in[11];
    const float* bo  = (const float*)d_in[12];
    const float* g1  = (const float*)d_in[13];
    const float* be1 = (const float*)d_in[14];
    const float* g2  = (const float*)d_in[15];
    const float* be2 = (const float*)d_in[16];
    const int* eidx  = (const int*)d_in[17];

    const int N = in_sizes[0] / 128;
    const int E = in_sizes[1] / 128;

    char* ws = (char*)d_ws;
    const size_t wbytes = (size_t)(32768 + 16384 + 16384 + 65536 + 65536) * 2;

    // ---- CSR-path layout ----
    size_t o_msg  = 0;                                     // E*128 bf16
    size_t o_att  = align256(o_msg + (size_t)E * 128 * 2); // E f32
    size_t o_eid  = align256(o_att + (size_t)E * 4);       // E i32
    size_t o_rp   = align256(o_eid + (size_t)E * 4);       // (N+1) i32
    size_t o_cnt  = align256(o_rp + (size_t)(N + 1) * 4);  // N i32 (cnt)
    size_t o_cur  = o_cnt + (size_t)N * 4;                 // N i32 (cursor), contiguous w/ cnt
    size_t o_hv1b = align256(o_cur + (size_t)N * 4);       // N*128 bf16
    size_t o_w    = align256(o_hv1b + (size_t)N * 128 * 2);
    size_t needed = o_w + wbytes;

    if (ws_size >= needed) {
        short* msg   = (short*)(ws + o_msg);
        float* att   = (float*)(ws + o_att);
        int*   eid   = (int*)(ws + o_eid);
        int*   rowp  = (int*)(ws + o_rp);
        int*   cnt   = (int*)(ws + o_cnt);
        int*   cur   = (int*)(ws + o_cur);
        short* hv1b  = (short*)(ws + o_hv1b);
        short* w1t   = (short*)(ws + o_w);
        short* w2t   = w1t + 32768;
        short* w3t   = w2t + 16384;
        short* wit   = w3t + 16384;
        short* wot   = wit + 65536;

        hipMemsetAsync(ws + o_cnt, 0, (size_t)2 * N * 4, stream);  // cnt + cursor
        prep_kernel<<<256, 256, 0, stream>>>(w1, w2, w3, wi, wo, w1t, w2t, w3t, wit, wot);
        csr_count_kernel<<<(E + 255) / 256, 256, 0, stream>>>(eidx, E, cnt);
        csr_scan_kernel<<<1, 1024, 0, stream>>>(cnt, N, rowp);
        csr_scatter_kernel<<<(E + 255) / 256, 256, 0, stream>>>(eidx, E, rowp, cur, eid);
        edge_kernel<1><<<(E + 63) / 64, 256, 0, stream>>>(hV, hE, eidx, E, w1t, w2t, w3t,
                                                          b1, b2, b3, Av,
                                                          nullptr, nullptr, msg, att);
        node1_csr_kernel<<<(N + 3) / 4, 256, 0, stream>>>(hV, msg, att, rowp, eid,
                                                          g1, be1, N, hv1b);
        ffn_kernel<<<(N + 31) / 32, 256, 0, stream>>>(hv1b, wit, wot, bi, bo, g2, be2,
                                                      N, (float*)d_out);
    } else {
        // ---- atomic fallback (previous structure) ----
        size_t f_num  = 0;                                              // N*128 f32
        size_t f_den  = f_num + (size_t)N * 128 * 4;                    // N f32
        size_t f_hv1b = align256(f_den + (size_t)N * 4);                // N*128 bf16
        size_t f_w    = align256(f_hv1b + (size_t)N * 128 * 2);

        float* num   = (float*)(ws + f_num);
        float* den   = (float*)(ws + f_den);
        short* hv1b  = (short*)(ws + f_hv1b);
        short* w1t   = (short*)(ws + f_w);
        short* w2t   = w1t + 32768;
        short* w3t   = w2t + 16384;
        short* wit   = w3t + 16384;
        short* wot   = wit + 65536;

        hipMemsetAsync(ws, 0, f_den + (size_t)N * 4, stream);
        prep_kernel<<<256, 256, 0, stream>>>(w1, w2, w3, wi, wo, w1t, w2t, w3t, wit, wot);
        edge_kernel<0><<<(E + 63) / 64, 256, 0, stream>>>(hV, hE, eidx, E, w1t, w2t, w3t,
                                                          b1, b2, b3, Av,
                                                          num, den, nullptr, nullptr);
        node1_kernel<<<(N + 3) / 4, 256, 0, stream>>>(hV, num, den, g1, be1, N, hv1b);
        ffn_kernel<<<(N + 31) / 32, 256, 0, stream>>>(hv1b, wit, wot, bi, bo, g2, be2,
                                                      N, (float*)d_out);
    }
}

// Round 6
// 691.493 us; speedup vs baseline: 1.0932x; 1.0932x over previous
//
#include <hip/hip_runtime.h>
#include <stdint.h>

// GNN layer on MI355X. Inputs f32, output f32 (per reference). Edge MLP via
// bf16 MFMA (f32 accum). Scatter-reduce over dst via CSR sort + gather.
// R5: edge kernel rebuilt for occupancy — 8 waves/block (16 cols each),
// LDS overlay (H1/H2 reuse dead M region): 52.7->37.4 KB, acc 32->16 VGPR.
// Target: 32 waves/CU (was 12). node1_csr: eid software prefetch.

typedef __attribute__((ext_vector_type(8))) short short8;   // 8 bf16 = 4 VGPRs
typedef __attribute__((ext_vector_type(4))) float floatx4;  // MFMA C/D

__device__ __forceinline__ float b2f(short s) {
    union { float f; uint32_t u; } v; v.u = ((uint32_t)(uint16_t)s) << 16; return v.f;
}
__device__ __forceinline__ short f2b(float f) {
    union { float f; uint32_t u; } v; v.f = f;
    uint32_t u = v.u;
    uint32_t r = (u + 0x7fff + ((u >> 16) & 1)) >> 16;  // RNE
    return (short)r;
}

#define NEG 0.01f

// ---------------- weight canonicalization f32 -> bf16, transposed ----------
__global__ void prep_kernel(const float* __restrict__ w1, const float* __restrict__ w2,
                            const float* __restrict__ w3, const float* __restrict__ wi,
                            const float* __restrict__ wo,
                            short* __restrict__ w1t, short* __restrict__ w2t,
                            short* __restrict__ w3t, short* __restrict__ wit,
                            short* __restrict__ wot) {
    int t = blockIdx.x * 256 + threadIdx.x;  // 65536 threads
    if (t < 32768) { int k = t >> 7, n = t & 127; w1t[n * 256 + k] = f2b(w1[t]); }
    if (t < 16384) {
        int k = t >> 7, n = t & 127;
        w2t[n * 128 + k] = f2b(w2[t]);
        w3t[n * 128 + k] = f2b(w3[t]);
    }
    { int k = t >> 9, n = t & 511; wit[n * 128 + k] = f2b(wi[t]); }
    { int k = t >> 7, n = t & 127; wot[n * 512 + k] = f2b(wo[t]); }
}

// ---------------- CSR build ----------------
__global__ void csr_count_kernel(const int* __restrict__ dst, int E, int* __restrict__ cnt) {
    int e = blockIdx.x * 256 + threadIdx.x;
    if (e < E) atomicAdd(&cnt[dst[e]], 1);
}

__global__ __launch_bounds__(1024) void csr_scan_kernel(const int* __restrict__ cnt,
                                                        int N, int* __restrict__ rowptr) {
    __shared__ int part[1024];
    int t = threadIdx.x;
    int per = (N + 1023) >> 10;
    int beg = t * per;
    int end = beg + per; if (end > N) end = N; if (beg > N) beg = N;
    int s = 0;
    for (int i = beg; i < end; ++i) s += cnt[i];
    part[t] = s;
    __syncthreads();
    for (int off = 1; off < 1024; off <<= 1) {
        int v = (t >= off) ? part[t - off] : 0;
        __syncthreads();
        part[t] += v;
        __syncthreads();
    }
    int run = part[t] - s;  // exclusive prefix
    for (int i = beg; i < end; ++i) { rowptr[i] = run; run += cnt[i]; }
    if (t == 1023) rowptr[N] = part[1023];
}

__global__ void csr_scatter_kernel(const int* __restrict__ dst, int E,
                                   const int* __restrict__ rowptr,
                                   int* __restrict__ cursor, int* __restrict__ eid) {
    int e = blockIdx.x * 256 + threadIdx.x;
    if (e < E) {
        int d = dst[e];
        int p = atomicAdd(&cursor[d], 1);
        eid[rowptr[d] + p] = e;
    }
}

// ---------------- edge kernel ----------------
// 64 edges/block, 512 threads (8 waves). Wave w owns output cols [16w,16w+16).
// LDS: smM holds M (stride 264) during staging/att/layer1, then is overlaid:
//   H1 @ offset 0 (stride 136), H2 @ offset 8704 (stride 136).
// MODE 0: atomic scatter into num/denom.  MODE 1: write bf16 msg rows + att.
template <int MODE>
__global__ __launch_bounds__(512, 8) void edge_kernel(
    const float* __restrict__ hV, const float* __restrict__ hE,
    const int* __restrict__ dst, int E,
    const short* __restrict__ w1t, const short* __restrict__ w2t,
    const short* __restrict__ w3t,
    const float* __restrict__ b1, const float* __restrict__ b2,
    const float* __restrict__ b3, const float* __restrict__ Av,
    float* __restrict__ num, float* __restrict__ denom,
    short* __restrict__ msg, float* __restrict__ att_g) {
    __shared__ short smM[64 * 272];   // 34816 B; M max idx 16895, H2 max idx 17399
    __shared__ float s_att[64];
    __shared__ int s_dst[64];
    __shared__ float s_part[64][4];

    const int tid = threadIdx.x;      // 0..511
    const int lane = tid & 63;
    const int wv = tid >> 6;          // 0..7
    const int e0 = blockIdx.x * 64;

    if (tid < 64) {
        int e = e0 + tid; if (e >= E) e = E - 1;
        s_dst[tid] = dst[e];
    }
    __syncthreads();                                   // B1: s_dst ready

    // stage M = [h_V[dst] | h_E] (64 rows x 256), f32 -> bf16; 2048 chunks / 512
#pragma unroll
    for (int i = 0; i < 4; ++i) {
        int c = tid + i * 512;
        int row = c >> 5;
        int off = (c & 31) * 8;
        int e = e0 + row; if (e >= E) e = E - 1;
        const float* src = (off < 128)
            ? (hV + (size_t)s_dst[row] * 128 + off)
            : (hE + (size_t)e * 128 + (off - 128));
        float4 a0 = *(const float4*)(src);
        float4 a1 = *(const float4*)(src + 4);
        short8 v;
        v[0] = f2b(a0.x); v[1] = f2b(a0.y); v[2] = f2b(a0.z); v[3] = f2b(a0.w);
        v[4] = f2b(a1.x); v[5] = f2b(a1.y); v[6] = f2b(a1.z); v[7] = f2b(a1.w);
        *(short8*)(&smM[row * 264 + off]) = v;
    }
    __syncthreads();                                   // B2: M staged

    // attention (identical numerics to R4: 256 threads, 4x64 partition)
    if (tid < 256) {
        int e = tid >> 2, p = tid & 3;
        const short* mr = &smM[e * 264 + p * 64];
        const float* ar = &Av[p * 64];
        float s = 0.f;
#pragma unroll 8
        for (int k = 0; k < 64; ++k) s += b2f(mr[k]) * ar[k];
        s_part[e][p] = s;
    }
    __syncthreads();                                   // B3: partials ready
    if (tid < 64) {
        float x = s_part[tid][0] + s_part[tid][1] + s_part[tid][2] + s_part[tid][3];
        float z = (x >= 0.f) ? x : NEG * x;
        float a = expf(1.f / (1.f + expf(-z)));
        s_att[tid] = a;
        if (e0 + tid < E) {
            if (MODE == 0) unsafeAtomicAdd(&denom[s_dst[tid]], a);
            else att_g[e0 + tid] = a;
        }
    }
    // no barrier here: s_att is only read after B5/B6/B7 below, which order
    // this phase's writes against all later readers.

    const int q = lane >> 4, r = lane & 15;
    const int cb = wv * 16;
    floatx4 zero = {0.f, 0.f, 0.f, 0.f};

    // ---- layer 1: h1 = lrelu(M @ w1 + b1), K=256 ----
    {
        floatx4 acc[4];
#pragma unroll
        for (int rt = 0; rt < 4; ++rt) acc[rt] = zero;
#pragma unroll
        for (int ks = 0; ks < 8; ++ks) {
            short8 bA = *(const short8*)(w1t + (cb + r) * 256 + ks * 32 + q * 8);
#pragma unroll
            for (int rt = 0; rt < 4; ++rt) {
                short8 a = *(const short8*)(&smM[(rt * 16 + r) * 264 + ks * 32 + q * 8]);
                acc[rt] = __builtin_amdgcn_mfma_f32_16x16x32_bf16(a, bA, acc[rt], 0, 0, 0);
            }
        }
        __syncthreads();                               // B5: all M reads done
        // write H1 into [0, 8704) shorts, stride 136 (aliases dead M)
        int col = cb + r;
        float bias = b1[col];
#pragma unroll
        for (int rt = 0; rt < 4; ++rt)
#pragma unroll
            for (int rr = 0; rr < 4; ++rr) {
                int row = rt * 16 + q * 4 + rr;
                float v = acc[rt][rr] + bias;
                v = (v >= 0.f) ? v : NEG * v;
                smM[row * 136 + col] = f2b(v);
            }
    }
    __syncthreads();                                   // B6: H1 ready

    // ---- layer 2: h2 = lrelu(h1 @ w2 + b2), K=128; H2 @ 8704 (disjoint) ----
    {
        floatx4 acc[4];
#pragma unroll
        for (int rt = 0; rt < 4; ++rt) acc[rt] = zero;
#pragma unroll
        for (int ks = 0; ks < 4; ++ks) {
            short8 bA = *(const short8*)(w2t + (cb + r) * 128 + ks * 32 + q * 8);
#pragma unroll
            for (int rt = 0; rt < 4; ++rt) {
                short8 a = *(const short8*)(&smM[(rt * 16 + r) * 136 + ks * 32 + q * 8]);
                acc[rt] = __builtin_amdgcn_mfma_f32_16x16x32_bf16(a, bA, acc[rt], 0, 0, 0);
            }
        }
        // H2 region [8704,17408) is disjoint from H1 [0,8704): no barrier needed
        int col = cb + r;
        float bias = b2[col];
#pragma unroll
        for (int rt = 0; rt < 4; ++rt)
#pragma unroll
            for (int rr = 0; rr < 4; ++rr) {
                int row = rt * 16 + q * 4 + rr;
                float v = acc[rt][rr] + bias;
                v = (v >= 0.f) ? v : NEG * v;
                smM[8704 + row * 136 + col] = f2b(v);
            }
    }
    __syncthreads();                                   // B7: H2 ready, H1 reads done

    // ---- layer 3: hm = h2 @ w3 + b3; weighted by att ----
    {
        floatx4 acc[4];
#pragma unroll
        for (int rt = 0; rt < 4; ++rt) acc[rt] = zero;
#pragma unroll
        for (int ks = 0; ks < 4; ++ks) {
            short8 bA = *(const short8*)(w3t + (cb + r) * 128 + ks * 32 + q * 8);
#pragma unroll
            for (int rt = 0; rt < 4; ++rt) {
                short8 a = *(const short8*)(&smM[8704 + (rt * 16 + r) * 136 + ks * 32 + q * 8]);
                acc[rt] = __builtin_amdgcn_mfma_f32_16x16x32_bf16(a, bA, acc[rt], 0, 0, 0);
            }
        }
        int col = cb + r;
        float bias = b3[col];
        if (MODE == 0) {
#pragma unroll
            for (int rt = 0; rt < 4; ++rt)
#pragma unroll
                for (int rr = 0; rr < 4; ++rr) {
                    int row = rt * 16 + q * 4 + rr;
                    if (e0 + row < E) {
                        float v = (acc[rt][rr] + bias) * s_att[row];
                        unsafeAtomicAdd(&num[(size_t)s_dst[row] * 128 + col], v);
                    }
                }
        } else {
            // stage weighted bf16 rows into H1 region (reads of H1 done at B7)
#pragma unroll
            for (int rt = 0; rt < 4; ++rt)
#pragma unroll
                for (int rr = 0; rr < 4; ++rr) {
                    int row = rt * 16 + q * 4 + rr;
                    float v = (acc[rt][rr] + bias) * s_att[row];
                    smM[row * 136 + col] = f2b(v);
                }
            __syncthreads();                           // B8: staged rows ready
#pragma unroll
            for (int p2 = 0; p2 < 2; ++p2) {
                int chunk = tid + p2 * 512;             // 0..1023
                int row = chunk >> 4;                   // 64 rows
                int off = (chunk & 15) * 8;             // 16B chunks
                if (e0 + row < E)
                    *(int4*)(msg + (size_t)(e0 + row) * 128 + off) =
                        *(const int4*)(&smM[row * 136 + off]);
            }
        }
    }
}

// ---------------- node LN1 (atomic-path variant) ----------------
__global__ __launch_bounds__(256) void node1_kernel(
    const float* __restrict__ hV, const float* __restrict__ num,
    const float* __restrict__ denom, const float* __restrict__ g1,
    const float* __restrict__ be1, int N, short* __restrict__ hv1b) {
    int n = blockIdx.x * 4 + (threadIdx.x >> 6);
    int lane = threadIdx.x & 63;
    if (n >= N) return;
    float d = denom[n];
    float inv = (d > 0.f) ? 1.f / (d * 30.f) : 0.f;
    size_t base = (size_t)n * 128;
    float x0 = hV[base + lane] + num[base + lane] * inv;
    float x1 = hV[base + lane + 64] + num[base + lane + 64] * inv;
    float s = x0 + x1, sq = x0 * x0 + x1 * x1;
#pragma unroll
    for (int o = 32; o > 0; o >>= 1) {
        s += __shfl_down(s, o);
        sq += __shfl_down(sq, o);
    }
    s = __shfl(s, 0); sq = __shfl(sq, 0);
    float mu = s * 0.0078125f;
    float var = sq * 0.0078125f - mu * mu;
    float rstd = rsqrtf(var + 1e-6f);
    float y0 = g1[lane] * (x0 - mu) * rstd + be1[lane];
    float y1 = g1[lane + 64] * (x1 - mu) * rstd + be1[lane + 64];
    hv1b[base + lane] = f2b(y0);
    hv1b[base + lane + 64] = f2b(y1);
}

// ---------------- node gather-reduce + LN1 (CSR path) ----------------
// 1 wave per node, 4 nodes/block. Lane handles cols 2*lane, 2*lane+1.
// eid software prefetch: overlap next eid load with current msg/att loads.
__global__ __launch_bounds__(256) void node1_csr_kernel(
    const float* __restrict__ hV, const short* __restrict__ msg,
    const float* __restrict__ att, const int* __restrict__ rowptr,
    const int* __restrict__ eid, const float* __restrict__ g1,
    const float* __restrict__ be1, int N, short* __restrict__ hv1b) {
    int n = blockIdx.x * 4 + (threadIdx.x >> 6);
    int lane = threadIdx.x & 63;
    if (n >= N) return;
    int beg = rowptr[n], end = rowptr[n + 1];
    float acc0 = 0.f, acc1 = 0.f, den = 0.f;
    if (beg < end) {
        int e = eid[beg];
        for (int i = beg + 1; i <= end; ++i) {
            int en = (i < end) ? eid[i] : e;      // prefetch next eid
            uint32_t m = *(const uint32_t*)(msg + (size_t)e * 128 + lane * 2);
            float a = att[e];
            acc0 += b2f((short)(m & 0xffffu));
            acc1 += b2f((short)(m >> 16));
            den += a;
            e = en;
        }
    }
    float inv = (den > 0.f) ? 1.f / (den * 30.f) : 0.f;
    size_t base = (size_t)n * 128;
    float2 h = *(const float2*)(hV + base + lane * 2);
    float x0 = h.x + acc0 * inv;
    float x1 = h.y + acc1 * inv;
    float s = x0 + x1, sq = x0 * x0 + x1 * x1;
#pragma unroll
    for (int o = 32; o > 0; o >>= 1) {
        s += __shfl_down(s, o);
        sq += __shfl_down(sq, o);
    }
    s = __shfl(s, 0); sq = __shfl(sq, 0);
    float mu = s * 0.0078125f;
    float var = sq * 0.0078125f - mu * mu;
    float rstd = rsqrtf(var + 1e-6f);
    float y0 = g1[lane * 2] * (x0 - mu) * rstd + be1[lane * 2];
    float y1 = g1[lane * 2 + 1] * (x1 - mu) * rstd + be1[lane * 2 + 1];
    uint32_t pack = (uint32_t)(uint16_t)f2b(y0) | ((uint32_t)(uint16_t)f2b(y1) << 16);
    *(uint32_t*)(hv1b + base + lane * 2) = pack;
}

// ---------------- FFN + LN2 (f32 output) ----------------
__global__ __launch_bounds__(256) void ffn_kernel(
    const short* __restrict__ hv1b,
    const short* __restrict__ wit, const short* __restrict__ wot,
    const float* __restrict__ bi, const float* __restrict__ bo,
    const float* __restrict__ g2, const float* __restrict__ be2,
    int N, float* __restrict__ out) {
    __shared__ short smX[32 * 136];
    __shared__ short smT[32 * 520];
    __shared__ float smD[32][128];
    __shared__ float smR[32][8][2];
    __shared__ float smS[32][2];

    const int tid = threadIdx.x;
    const int lane = tid & 63;
    const int wv = tid >> 6;
    const int nb = blockIdx.x * 32;

#pragma unroll
    for (int i = 0; i < 2; ++i) {
        int c = tid + i * 256;
        int row = c >> 4;
        int off = (c & 15) * 8;
        int n = nb + row; if (n >= N) n = N - 1;
        *(int4*)(&smX[row * 136 + off]) = *(const int4*)(hv1b + (size_t)n * 128 + off);
    }
    __syncthreads();

    const int q = lane >> 4, r = lane & 15;
    floatx4 zero = {0.f, 0.f, 0.f, 0.f};

    {   // T = relu(X @ wi + bi), K=128
        floatx4 acc[2][8];
#pragma unroll
        for (int ct = 0; ct < 8; ++ct) { acc[0][ct] = zero; acc[1][ct] = zero; }
        const int cb = wv * 128;
#pragma unroll
        for (int ks = 0; ks < 4; ++ks) {
            short8 a0 = *(const short8*)(&smX[r * 136 + ks * 32 + q * 8]);
            short8 a1 = *(const short8*)(&smX[(16 + r) * 136 + ks * 32 + q * 8]);
#pragma unroll
            for (int ct = 0; ct < 8; ++ct) {
                short8 b = *(const short8*)(wit + (size_t)(cb + ct * 16 + r) * 128 + ks * 32 + q * 8);
                acc[0][ct] = __builtin_amdgcn_mfma_f32_16x16x32_bf16(a0, b, acc[0][ct], 0, 0, 0);
                acc[1][ct] = __builtin_amdgcn_mfma_f32_16x16x32_bf16(a1, b, acc[1][ct], 0, 0, 0);
            }
        }
#pragma unroll
        for (int ct = 0; ct < 8; ++ct) {
            int col = cb + ct * 16 + r;
            float bias = bi[col];
#pragma unroll
            for (int rt = 0; rt < 2; ++rt)
#pragma unroll
                for (int rr = 0; rr < 4; ++rr) {
                    int row = rt * 16 + q * 4 + rr;
                    float v = acc[rt][ct][rr] + bias;
                    smT[row * 520 + col] = f2b(v > 0.f ? v : 0.f);
                }
        }
    }
    __syncthreads();

    {   // dh2 = T @ wo + bo, K=512
        floatx4 acc[2][2];
        acc[0][0] = zero; acc[0][1] = zero; acc[1][0] = zero; acc[1][1] = zero;
        const int cb = wv * 32;
#pragma unroll
        for (int ks = 0; ks < 16; ++ks) {
            short8 bA = *(const short8*)(wot + (size_t)(cb + r) * 512 + ks * 32 + q * 8);
            short8 bB = *(const short8*)(wot + (size_t)(cb + 16 + r) * 512 + ks * 32 + q * 8);
            short8 a0 = *(const short8*)(&smT[r * 520 + ks * 32 + q * 8]);
            short8 a1 = *(const short8*)(&smT[(16 + r) * 520 + ks * 32 + q * 8]);
            acc[0][0] = __builtin_amdgcn_mfma_f32_16x16x32_bf16(a0, bA, acc[0][0], 0, 0, 0);
            acc[0][1] = __builtin_amdgcn_mfma_f32_16x16x32_bf16(a0, bB, acc[0][1], 0, 0, 0);
            acc[1][0] = __builtin_amdgcn_mfma_f32_16x16x32_bf16(a1, bA, acc[1][0], 0, 0, 0);
            acc[1][1] = __builtin_amdgcn_mfma_f32_16x16x32_bf16(a1, bB, acc[1][1], 0, 0, 0);
        }
#pragma unroll
        for (int ct = 0; ct < 2; ++ct) {
            int col = cb + ct * 16 + r;
            float bias = bo[col];
#pragma unroll
            for (int rt = 0; rt < 2; ++rt)
#pragma unroll
                for (int rr = 0; rr < 4; ++rr) {
                    int row = rt * 16 + q * 4 + rr;
                    smD[row][col] = acc[rt][ct][rr] + bias;
                }
        }
    }
    __syncthreads();

    {   // LN2 over x = hv1 + dh2
        int row = tid >> 3, j = tid & 7;
        int n = nb + row;
        float s = 0.f, sq = 0.f;
#pragma unroll
        for (int c = j * 16; c < j * 16 + 16; ++c) {
            float x = (n < N ? b2f(hv1b[(size_t)n * 128 + c]) : 0.f) + smD[row][c];
            smD[row][c] = x;
            s += x; sq += x * x;
        }
        smR[row][j][0] = s; smR[row][j][1] = sq;
    }
    __syncthreads();
    if ((tid & 7) == 0) {
        int row = tid >> 3;
        float s = 0.f, sq = 0.f;
#pragma unroll
        for (int j = 0; j < 8; ++j) { s += smR[row][j][0]; sq += smR[row][j][1]; }
        float mu = s * 0.0078125f;
        float var = sq * 0.0078125f - mu * mu;
        smS[row][0] = mu;
        smS[row][1] = rsqrtf(var + 1e-6f);
    }
    __syncthreads();
    {
        int row = tid >> 3, j = tid & 7;
        int n = nb + row;
        if (n < N) {
            float mu = smS[row][0], rstd = smS[row][1];
#pragma unroll
            for (int c = j * 16; c < j * 16 + 16; ++c) {
                float y = g2[c] * (smD[row][c] - mu) * rstd + be2[c];
                out[(size_t)n * 128 + c] = y;   // f32 output
            }
        }
    }
}

static inline size_t align256(size_t x) { return (x + 255) & ~(size_t)255; }

extern "C" void kernel_launch(void* const* d_in, const int* in_sizes, int n_in,
                              void* d_out, int out_size, void* d_ws, size_t ws_size,
                              hipStream_t stream) {
    const float* hV  = (const float*)d_in[0];
    const float* hE  = (const float*)d_in[1];
    const float* w1  = (const float*)d_in[2];
    const float* b1  = (const float*)d_in[3];
    const float* w2  = (const float*)d_in[4];
    const float* b2  = (const float*)d_in[5];
    const float* w3  = (const float*)d_in[6];
    const float* b3  = (const float*)d_in[7];
    const float* Av  = (const float*)d_in[8];
    const float* wi  = (const float*)d_in[9];
    const float* bi  = (const float*)d_in[10];
    const float* wo  = (const float*)d_in[11];
    const float* bo  = (const float*)d_in[12];
    const float* g1  = (const float*)d_in[13];
    const float* be1 = (const float*)d_in[14];
    const float* g2  = (const float*)d_in[15];
    const float* be2 = (const float*)d_in[16];
    const int* eidx  = (const int*)d_in[17];

    const int N = in_sizes[0] / 128;
    const int E = in_sizes[1] / 128;

    char* ws = (char*)d_ws;
    const size_t wbytes = (size_t)(32768 + 16384 + 16384 + 65536 + 65536) * 2;

    // ---- CSR-path layout ----
    size_t o_msg  = 0;                                     // E*128 bf16
    size_t o_att  = align256(o_msg + (size_t)E * 128 * 2); // E f32
    size_t o_eid  = align256(o_att + (size_t)E * 4);       // E i32
    size_t o_rp   = align256(o_eid + (size_t)E * 4);       // (N+1) i32
    size_t o_cnt  = align256(o_rp + (size_t)(N + 1) * 4);  // N i32 (cnt)
    size_t o_cur  = o_cnt + (size_t)N * 4;                 // N i32 (cursor), contiguous w/ cnt
    size_t o_hv1b = align256(o_cur + (size_t)N * 4);       // N*128 bf16
    size_t o_w    = align256(o_hv1b + (size_t)N * 128 * 2);
    size_t needed = o_w + wbytes;

    if (ws_size >= needed) {
        short* msg   = (short*)(ws + o_msg);
        float* att   = (float*)(ws + o_att);
        int*   eid   = (int*)(ws + o_eid);
        int*   rowp  = (int*)(ws + o_rp);
        int*   cnt   = (int*)(ws + o_cnt);
        int*   cur   = (int*)(ws + o_cur);
        short* hv1b  = (short*)(ws + o_hv1b);
        short* w1t   = (short*)(ws + o_w);
        short* w2t   = w1t + 32768;
        short* w3t   = w2t + 16384;
        short* wit   = w3t + 16384;
        short* wot   = wit + 65536;

        hipMemsetAsync(ws + o_cnt, 0, (size_t)2 * N * 4, stream);  // cnt + cursor
        prep_kernel<<<256, 256, 0, stream>>>(w1, w2, w3, wi, wo, w1t, w2t, w3t, wit, wot);
        csr_count_kernel<<<(E + 255) / 256, 256, 0, stream>>>(eidx, E, cnt);
        csr_scan_kernel<<<1, 1024, 0, stream>>>(cnt, N, rowp);
        csr_scatter_kernel<<<(E + 255) / 256, 256, 0, stream>>>(eidx, E, rowp, cur, eid);
        edge_kernel<1><<<(E + 63) / 64, 512, 0, stream>>>(hV, hE, eidx, E, w1t, w2t, w3t,
                                                          b1, b2, b3, Av,
                                                          nullptr, nullptr, msg, att);
        node1_csr_kernel<<<(N + 3) / 4, 256, 0, stream>>>(hV, msg, att, rowp, eid,
                                                          g1, be1, N, hv1b);
        ffn_kernel<<<(N + 31) / 32, 256, 0, stream>>>(hv1b, wit, wot, bi, bo, g2, be2,
                                                      N, (float*)d_out);
    } else {
        // ---- atomic fallback ----
        size_t f_num  = 0;                                              // N*128 f32
        size_t f_den  = f_num + (size_t)N * 128 * 4;                    // N f32
        size_t f_hv1b = align256(f_den + (size_t)N * 4);                // N*128 bf16
        size_t f_w    = align256(f_hv1b + (size_t)N * 128 * 2);

        float* num   = (float*)(ws + f_num);
        float* den   = (float*)(ws + f_den);
        short* hv1b  = (short*)(ws + f_hv1b);
        short* w1t   = (short*)(ws + f_w);
        short* w2t   = w1t + 32768;
        short* w3t   = w2t + 16384;
        short* wit   = w3t + 16384;
        short* wot   = wit + 65536;

        hipMemsetAsync(ws, 0, f_den + (size_t)N * 4, stream);
        prep_kernel<<<256, 256, 0, stream>>>(w1, w2, w3, wi, wo, w1t, w2t, w3t, wit, wot);
        edge_kernel<0><<<(E + 63) / 64, 512, 0, stream>>>(hV, hE, eidx, E, w1t, w2t, w3t,
                                                          b1, b2, b3, Av,
                                                          num, den, nullptr, nullptr);
        node1_kernel<<<(N + 3) / 4, 256, 0, stream>>>(hV, num, den, g1, be1, N, hv1b);
        ffn_kernel<<<(N + 31) / 32, 256, 0, stream>>>(hv1b, wit, wot, bi, bo, g2, be2,
                                                      N, (float*)d_out);
    }
}

// Round 8
// 677.132 us; speedup vs baseline: 1.1164x; 1.0212x over previous
//
#include <hip/hip_runtime.h>
#include <stdint.h>

// GNN layer on MI355X. Inputs f32, output f32 (per reference). Edge MLP via
// bf16 MFMA (f32 accum). CSR sort + gather (no f32 atomics) when ws permits.
// R6: edge kernel — attention fused into layer-1 MFMA (extra w1a tile, row 0
// = A); MFMA operands swapped so each lane holds 4 consecutive out-cols of
// one edge -> packed ds_write_b64 epilogues; barriers 8->6. ffn: smD
// overlaid into smT (+1 barrier), LDS 60.7->44.3 KB (3 blocks/CU).
// node1_csr: 2-edge unroll.
// R7: fix — 'short4' collides with HIP's built-in vector type; renamed bhalf4.

typedef __attribute__((ext_vector_type(8))) short short8;   // 8 bf16 = 4 VGPRs
typedef __attribute__((ext_vector_type(4))) short bhalf4;   // 4 bf16 = 8 B
typedef __attribute__((ext_vector_type(4))) float floatx4;  // MFMA C/D

__device__ __forceinline__ float b2f(short s) {
    union { float f; uint32_t u; } v; v.u = ((uint32_t)(uint16_t)s) << 16; return v.f;
}
__device__ __forceinline__ short f2b(float f) {
    union { float f; uint32_t u; } v; v.f = f;
    uint32_t u = v.u;
    uint32_t r = (u + 0x7fff + ((u >> 16) & 1)) >> 16;  // RNE
    return (short)r;
}

#define NEG 0.01f

// ---------------- weight canonicalization f32 -> bf16, transposed ----------
// Also builds w1a [16][256]: row 0 = Av (bf16), rows 1..15 = 0.
__global__ void prep_kernel(const float* __restrict__ w1, const float* __restrict__ w2,
                            const float* __restrict__ w3, const float* __restrict__ wi,
                            const float* __restrict__ wo, const float* __restrict__ Av,
                            short* __restrict__ w1t, short* __restrict__ w2t,
                            short* __restrict__ w3t, short* __restrict__ wit,
                            short* __restrict__ wot, short* __restrict__ w1a) {
    int t = blockIdx.x * 256 + threadIdx.x;  // 65536 threads
    if (t < 32768) { int k = t >> 7, n = t & 127; w1t[n * 256 + k] = f2b(w1[t]); }
    if (t < 16384) {
        int k = t >> 7, n = t & 127;
        w2t[n * 128 + k] = f2b(w2[t]);
        w3t[n * 128 + k] = f2b(w3[t]);
    }
    if (t < 4096) w1a[t] = (t < 256) ? f2b(Av[t]) : (short)0;
    { int k = t >> 9, n = t & 511; wit[n * 128 + k] = f2b(wi[t]); }
    { int k = t >> 7, n = t & 127; wot[n * 512 + k] = f2b(wo[t]); }
}

// ---------------- CSR build ----------------
__global__ void csr_count_kernel(const int* __restrict__ dst, int E, int* __restrict__ cnt) {
    int e = blockIdx.x * 256 + threadIdx.x;
    if (e < E) atomicAdd(&cnt[dst[e]], 1);
}

__global__ __launch_bounds__(1024) void csr_scan_kernel(const int* __restrict__ cnt,
                                                        int N, int* __restrict__ rowptr) {
    __shared__ int part[1024];
    int t = threadIdx.x;
    int per = (N + 1023) >> 10;
    int beg = t * per;
    int end = beg + per; if (end > N) end = N; if (beg > N) beg = N;
    int s = 0;
    for (int i = beg; i < end; ++i) s += cnt[i];
    part[t] = s;
    __syncthreads();
    for (int off = 1; off < 1024; off <<= 1) {
        int v = (t >= off) ? part[t - off] : 0;
        __syncthreads();
        part[t] += v;
        __syncthreads();
    }
    int run = part[t] - s;  // exclusive prefix
    for (int i = beg; i < end; ++i) { rowptr[i] = run; run += cnt[i]; }
    if (t == 1023) rowptr[N] = part[1023];
}

__global__ void csr_scatter_kernel(const int* __restrict__ dst, int E,
                                   const int* __restrict__ rowptr,
                                   int* __restrict__ cursor, int* __restrict__ eid) {
    int e = blockIdx.x * 256 + threadIdx.x;
    if (e < E) {
        int d = dst[e];
        int p = atomicAdd(&cursor[d], 1);
        eid[rowptr[d] + p] = e;
    }
}

// ---------------- edge kernel ----------------
// 64 edges/block, 512 threads (8 waves). Wave w owns output cols [16w,16w+16).
// MFMA operand order: mfma(Wtile, Mtile, acc) -> lane (q=lane>>4, r=lane&15)
// holds edge row (16rt + r), cols (cb + 4q + rr). Waves 0..3 additionally
// compute att dots via w1a tile fused into the layer-1 ks loop (rt == wv).
// LDS: smM = M (stride 264) then overlaid H1 @0 / H2 @8704 (stride 136).
template <int MODE>
__global__ __launch_bounds__(512, 8) void edge_kernel(
    const float* __restrict__ hV, const float* __restrict__ hE,
    const int* __restrict__ dst, int E,
    const short* __restrict__ w1t, const short* __restrict__ w2t,
    const short* __restrict__ w3t, const short* __restrict__ w1a,
    const float* __restrict__ b1, const float* __restrict__ b2,
    const float* __restrict__ b3,
    float* __restrict__ num, float* __restrict__ denom,
    short* __restrict__ msg, float* __restrict__ att_g) {
    __shared__ short smM[64 * 272];   // 34816 B
    __shared__ float s_att[64];
    __shared__ int s_dst[64];

    const int tid = threadIdx.x;      // 0..511
    const int lane = tid & 63;
    const int wv = tid >> 6;          // 0..7
    const int e0 = blockIdx.x * 64;

    if (tid < 64) {
        int e = e0 + tid; if (e >= E) e = E - 1;
        s_dst[tid] = dst[e];
    }
    __syncthreads();                                   // B1: s_dst ready

    // stage M = [h_V[dst] | h_E] (64 rows x 256), f32 -> bf16
#pragma unroll
    for (int i = 0; i < 4; ++i) {
        int c = tid + i * 512;
        int row = c >> 5;
        int off = (c & 31) * 8;
        int e = e0 + row; if (e >= E) e = E - 1;
        const float* src = (off < 128)
            ? (hV + (size_t)s_dst[row] * 128 + off)
            : (hE + (size_t)e * 128 + (off - 128));
        float4 a0 = *(const float4*)(src);
        float4 a1 = *(const float4*)(src + 4);
        short8 v;
        v[0] = f2b(a0.x); v[1] = f2b(a0.y); v[2] = f2b(a0.z); v[3] = f2b(a0.w);
        v[4] = f2b(a1.x); v[5] = f2b(a1.y); v[6] = f2b(a1.z); v[7] = f2b(a1.w);
        *(short8*)(&smM[row * 264 + off]) = v;
    }
    __syncthreads();                                   // B2: M staged

    const int r = lane & 15, q = lane >> 4;
    const int cb = wv * 16;
    floatx4 zero = {0.f, 0.f, 0.f, 0.f};

    // ---- layer 1 (+fused att): K=256 ----
    floatx4 acc1[4];
    floatx4 accA = zero;
#pragma unroll
    for (int rt = 0; rt < 4; ++rt) acc1[rt] = zero;
#pragma unroll
    for (int ks = 0; ks < 8; ++ks) {
        short8 wA = *(const short8*)(w1t + (cb + r) * 256 + ks * 32 + q * 8);
        short8 avA = {0, 0, 0, 0, 0, 0, 0, 0};
        if (wv < 4) avA = *(const short8*)(w1a + r * 256 + ks * 32 + q * 8);
#pragma unroll
        for (int rt = 0; rt < 4; ++rt) {
            short8 m = *(const short8*)(&smM[(rt * 16 + r) * 264 + ks * 32 + q * 8]);
            acc1[rt] = __builtin_amdgcn_mfma_f32_16x16x32_bf16(wA, m, acc1[rt], 0, 0, 0);
            if (wv == rt)   // wave-uniform (rt compile-time): waves 0..3 only
                accA = __builtin_amdgcn_mfma_f32_16x16x32_bf16(avA, m, accA, 0, 0, 0);
        }
    }
    __syncthreads();                                   // B3: all M reads done

    // att finalize: wave t (t<4), lanes q==0 hold dot for edge 16t + r (reg 0)
    if (wv < 4 && q == 0) {
        float x = accA[0];
        float z = (x >= 0.f) ? x : NEG * x;
        float a = expf(1.f / (1.f + expf(-z)));
        int edge = wv * 16 + r;
        s_att[edge] = a;
        if (e0 + edge < E) {
            if (MODE == 0) unsafeAtomicAdd(&denom[s_dst[edge]], a);
            else att_g[e0 + edge] = a;
        }
    }
    // H1 epilogue: packed b64 writes (4 consecutive cols per lane)
    {
        float4 bb = *(const float4*)(b1 + cb + q * 4);
        const float* bp = &bb.x;
#pragma unroll
        for (int rt = 0; rt < 4; ++rt) {
            bhalf4 pk;
#pragma unroll
            for (int rr = 0; rr < 4; ++rr) {
                float v = acc1[rt][rr] + bp[rr];
                v = (v >= 0.f) ? v : NEG * v;
                pk[rr] = f2b(v);
            }
            *(bhalf4*)(&smM[(rt * 16 + r) * 136 + cb + q * 4]) = pk;
        }
    }
    __syncthreads();                                   // B4: H1 + s_att ready

    // ---- layer 2: K=128; H2 @ 8704 shorts (disjoint from H1) ----
    {
        floatx4 acc2[4];
#pragma unroll
        for (int rt = 0; rt < 4; ++rt) acc2[rt] = zero;
#pragma unroll
        for (int ks = 0; ks < 4; ++ks) {
            short8 wA = *(const short8*)(w2t + (cb + r) * 128 + ks * 32 + q * 8);
#pragma unroll
            for (int rt = 0; rt < 4; ++rt) {
                short8 h = *(const short8*)(&smM[(rt * 16 + r) * 136 + ks * 32 + q * 8]);
                acc2[rt] = __builtin_amdgcn_mfma_f32_16x16x32_bf16(wA, h, acc2[rt], 0, 0, 0);
            }
        }
        float4 bb = *(const float4*)(b2 + cb + q * 4);
        const float* bp = &bb.x;
#pragma unroll
        for (int rt = 0; rt < 4; ++rt) {
            bhalf4 pk;
#pragma unroll
            for (int rr = 0; rr < 4; ++rr) {
                float v = acc2[rt][rr] + bp[rr];
                v = (v >= 0.f) ? v : NEG * v;
                pk[rr] = f2b(v);
            }
            *(bhalf4*)(&smM[8704 + (rt * 16 + r) * 136 + cb + q * 4]) = pk;
        }
    }
    __syncthreads();                                   // B5: H2 ready, H1 reads done

    // ---- layer 3: hm = h2 @ w3 + b3; weighted by att ----
    {
        floatx4 acc3[4];
#pragma unroll
        for (int rt = 0; rt < 4; ++rt) acc3[rt] = zero;
#pragma unroll
        for (int ks = 0; ks < 4; ++ks) {
            short8 wA = *(const short8*)(w3t + (cb + r) * 128 + ks * 32 + q * 8);
#pragma unroll
            for (int rt = 0; rt < 4; ++rt) {
                short8 h = *(const short8*)(&smM[8704 + (rt * 16 + r) * 136 + ks * 32 + q * 8]);
                acc3[rt] = __builtin_amdgcn_mfma_f32_16x16x32_bf16(wA, h, acc3[rt], 0, 0, 0);
            }
        }
        float4 bb = *(const float4*)(b3 + cb + q * 4);
        const float* bp = &bb.x;
        if (MODE == 0) {
#pragma unroll
            for (int rt = 0; rt < 4; ++rt) {
                int edge = rt * 16 + r;
                if (e0 + edge < E) {
                    float a = s_att[edge];
                    int dn = s_dst[edge];
#pragma unroll
                    for (int rr = 0; rr < 4; ++rr) {
                        float v = (acc3[rt][rr] + bp[rr]) * a;
                        unsafeAtomicAdd(&num[(size_t)dn * 128 + cb + q * 4 + rr], v);
                    }
                }
            }
        } else {
            // stage att-weighted rows into H1 region (reads done at B5)
#pragma unroll
            for (int rt = 0; rt < 4; ++rt) {
                int edge = rt * 16 + r;
                float a = s_att[edge];
                bhalf4 pk;
#pragma unroll
                for (int rr = 0; rr < 4; ++rr)
                    pk[rr] = f2b((acc3[rt][rr] + bp[rr]) * a);
                *(bhalf4*)(&smM[edge * 136 + cb + q * 4]) = pk;
            }
            __syncthreads();                           // B6: staged rows ready
#pragma unroll
            for (int p2 = 0; p2 < 2; ++p2) {
                int chunk = tid + p2 * 512;             // 0..1023
                int row = chunk >> 4;                   // 64 rows
                int off = (chunk & 15) * 8;             // 16B chunks
                if (e0 + row < E)
                    *(int4*)(msg + (size_t)(e0 + row) * 128 + off) =
                        *(const int4*)(&smM[row * 136 + off]);
            }
        }
    }
}

// ---------------- node LN1 (atomic-path variant) ----------------
__global__ __launch_bounds__(256) void node1_kernel(
    const float* __restrict__ hV, const float* __restrict__ num,
    const float* __restrict__ denom, const float* __restrict__ g1,
    const float* __restrict__ be1, int N, short* __restrict__ hv1b) {
    int n = blockIdx.x * 4 + (threadIdx.x >> 6);
    int lane = threadIdx.x & 63;
    if (n >= N) return;
    float d = denom[n];
    float inv = (d > 0.f) ? 1.f / (d * 30.f) : 0.f;
    size_t base = (size_t)n * 128;
    float x0 = hV[base + lane] + num[base + lane] * inv;
    float x1 = hV[base + lane + 64] + num[base + lane + 64] * inv;
    float s = x0 + x1, sq = x0 * x0 + x1 * x1;
#pragma unroll
    for (int o = 32; o > 0; o >>= 1) {
        s += __shfl_down(s, o);
        sq += __shfl_down(sq, o);
    }
    s = __shfl(s, 0); sq = __shfl(sq, 0);
    float mu = s * 0.0078125f;
    float var = sq * 0.0078125f - mu * mu;
    float rstd = rsqrtf(var + 1e-6f);
    float y0 = g1[lane] * (x0 - mu) * rstd + be1[lane];
    float y1 = g1[lane + 64] * (x1 - mu) * rstd + be1[lane + 64];
    hv1b[base + lane] = f2b(y0);
    hv1b[base + lane + 64] = f2b(y1);
}

// ---------------- node gather-reduce + LN1 (CSR path) ----------------
// 1 wave per node, 4 nodes/block. Lane handles cols 2*lane, 2*lane+1.
// 2-edge unroll: two msg/att loads in flight; summation order unchanged.
__global__ __launch_bounds__(256) void node1_csr_kernel(
    const float* __restrict__ hV, const short* __restrict__ msg,
    const float* __restrict__ att, const int* __restrict__ rowptr,
    const int* __restrict__ eid, const float* __restrict__ g1,
    const float* __restrict__ be1, int N, short* __restrict__ hv1b) {
    int n = blockIdx.x * 4 + (threadIdx.x >> 6);
    int lane = threadIdx.x & 63;
    if (n >= N) return;
    int beg = rowptr[n], end = rowptr[n + 1];
    float acc0 = 0.f, acc1 = 0.f, den = 0.f;
    int i = beg;
    for (; i + 2 <= end; i += 2) {
        int ea = eid[i], eb = eid[i + 1];
        uint32_t ma = *(const uint32_t*)(msg + (size_t)ea * 128 + lane * 2);
        uint32_t mb = *(const uint32_t*)(msg + (size_t)eb * 128 + lane * 2);
        float aa = att[ea], ab = att[eb];
        acc0 += b2f((short)(ma & 0xffffu));
        acc1 += b2f((short)(ma >> 16));
        den += aa;
        acc0 += b2f((short)(mb & 0xffffu));
        acc1 += b2f((short)(mb >> 16));
        den += ab;
    }
    if (i < end) {
        int e = eid[i];
        uint32_t m = *(const uint32_t*)(msg + (size_t)e * 128 + lane * 2);
        float a = att[e];
        acc0 += b2f((short)(m & 0xffffu));
        acc1 += b2f((short)(m >> 16));
        den += a;
    }
    float inv = (den > 0.f) ? 1.f / (den * 30.f) : 0.f;
    size_t base = (size_t)n * 128;
    float2 h = *(const float2*)(hV + base + lane * 2);
    float x0 = h.x + acc0 * inv;
    float x1 = h.y + acc1 * inv;
    float s = x0 + x1, sq = x0 * x0 + x1 * x1;
#pragma unroll
    for (int o = 32; o > 0; o >>= 1) {
        s += __shfl_down(s, o);
        sq += __shfl_down(sq, o);
    }
    s = __shfl(s, 0); sq = __shfl(sq, 0);
    float mu = s * 0.0078125f;
    float var = sq * 0.0078125f - mu * mu;
    float rstd = rsqrtf(var + 1e-6f);
    float y0 = g1[lane * 2] * (x0 - mu) * rstd + be1[lane * 2];
    float y1 = g1[lane * 2 + 1] * (x1 - mu) * rstd + be1[lane * 2 + 1];
    uint32_t pack = (uint32_t)(uint16_t)f2b(y0) | ((uint32_t)(uint16_t)f2b(y1) << 16);
    *(uint32_t*)(hv1b + base + lane * 2) = pack;
}

// ---------------- FFN + LN2 (f32 output) ----------------
// R6: smD overlaid into smT region (extra barrier after phase-2 MFMA reads).
// LDS 60.7 -> 44.3 KB -> 3 blocks/CU.
__global__ __launch_bounds__(256) void ffn_kernel(
    const short* __restrict__ hv1b,
    const short* __restrict__ wit, const short* __restrict__ wot,
    const float* __restrict__ bi, const float* __restrict__ bo,
    const float* __restrict__ g2, const float* __restrict__ be2,
    int N, float* __restrict__ out) {
    __shared__ short smX[32 * 136];
    __shared__ short smT[32 * 520];   // phase-2 input; later overlaid by dh f32 [32][132]
    __shared__ float smR[32][8][2];
    __shared__ float smS[32][2];
    float* smDT = (float*)smT;        // stride 132 floats

    const int tid = threadIdx.x;
    const int lane = tid & 63;
    const int wv = tid >> 6;
    const int nb = blockIdx.x * 32;

#pragma unroll
    for (int i = 0; i < 2; ++i) {
        int c = tid + i * 256;
        int row = c >> 4;
        int off = (c & 15) * 8;
        int n = nb + row; if (n >= N) n = N - 1;
        *(int4*)(&smX[row * 136 + off]) = *(const int4*)(hv1b + (size_t)n * 128 + off);
    }
    __syncthreads();

    const int q = lane >> 4, r = lane & 15;
    floatx4 zero = {0.f, 0.f, 0.f, 0.f};

    {   // T = relu(X @ wi + bi), K=128
        floatx4 acc[2][8];
#pragma unroll
        for (int ct = 0; ct < 8; ++ct) { acc[0][ct] = zero; acc[1][ct] = zero; }
        const int cb = wv * 128;
#pragma unroll
        for (int ks = 0; ks < 4; ++ks) {
            short8 a0 = *(const short8*)(&smX[r * 136 + ks * 32 + q * 8]);
            short8 a1 = *(const short8*)(&smX[(16 + r) * 136 + ks * 32 + q * 8]);
#pragma unroll
            for (int ct = 0; ct < 8; ++ct) {
                short8 b = *(const short8*)(wit + (size_t)(cb + ct * 16 + r) * 128 + ks * 32 + q * 8);
                acc[0][ct] = __builtin_amdgcn_mfma_f32_16x16x32_bf16(a0, b, acc[0][ct], 0, 0, 0);
                acc[1][ct] = __builtin_amdgcn_mfma_f32_16x16x32_bf16(a1, b, acc[1][ct], 0, 0, 0);
            }
        }
#pragma unroll
        for (int ct = 0; ct < 8; ++ct) {
            int col = cb + ct * 16 + r;
            float bias = bi[col];
#pragma unroll
            for (int rt = 0; rt < 2; ++rt)
#pragma unroll
                for (int rr = 0; rr < 4; ++rr) {
                    int row = rt * 16 + q * 4 + rr;
                    float v = acc[rt][ct][rr] + bias;
                    smT[row * 520 + col] = f2b(v > 0.f ? v : 0.f);
                }
        }
    }
    __syncthreads();

    {   // dh2 = T @ wo + bo, K=512
        floatx4 acc[2][2];
        acc[0][0] = zero; acc[0][1] = zero; acc[1][0] = zero; acc[1][1] = zero;
        const int cb = wv * 32;
#pragma unroll
        for (int ks = 0; ks < 16; ++ks) {
            short8 bA = *(const short8*)(wot + (size_t)(cb + r) * 512 + ks * 32 + q * 8);
            short8 bB = *(const short8*)(wot + (size_t)(cb + 16 + r) * 512 + ks * 32 + q * 8);
            short8 a0 = *(const short8*)(&smT[r * 520 + ks * 32 + q * 8]);
            short8 a1 = *(const short8*)(&smT[(16 + r) * 520 + ks * 32 + q * 8]);
            acc[0][0] = __builtin_amdgcn_mfma_f32_16x16x32_bf16(a0, bA, acc[0][0], 0, 0, 0);
            acc[0][1] = __builtin_amdgcn_mfma_f32_16x16x32_bf16(a0, bB, acc[0][1], 0, 0, 0);
            acc[1][0] = __builtin_amdgcn_mfma_f32_16x16x32_bf16(a1, bA, acc[1][0], 0, 0, 0);
            acc[1][1] = __builtin_amdgcn_mfma_f32_16x16x32_bf16(a1, bB, acc[1][1], 0, 0, 0);
        }
        __syncthreads();   // all smT reads done before overlay writes
#pragma unroll
        for (int ct = 0; ct < 2; ++ct) {
            int col = cb + ct * 16 + r;
            float bias = bo[col];
#pragma unroll
            for (int rt = 0; rt < 2; ++rt)
#pragma unroll
                for (int rr = 0; rr < 4; ++rr) {
                    int row = rt * 16 + q * 4 + rr;
                    smDT[row * 132 + col] = acc[rt][ct][rr] + bias;
                }
        }
    }
    __syncthreads();

    {   // LN2 over x = hv1 + dh2
        int row = tid >> 3, j = tid & 7;
        int n = nb + row;
        float s = 0.f, sq = 0.f;
#pragma unroll
        for (int c = j * 16; c < j * 16 + 16; ++c) {
            float x = (n < N ? b2f(hv1b[(size_t)n * 128 + c]) : 0.f) + smDT[row * 132 + c];
            smDT[row * 132 + c] = x;
            s += x; sq += x * x;
        }
        smR[row][j][0] = s; smR[row][j][1] = sq;
    }
    __syncthreads();
    if ((tid & 7) == 0) {
        int row = tid >> 3;
        float s = 0.f, sq = 0.f;
#pragma unroll
        for (int j = 0; j < 8; ++j) { s += smR[row][j][0]; sq += smR[row][j][1]; }
        float mu = s * 0.0078125f;
        float var = sq * 0.0078125f - mu * mu;
        smS[row][0] = mu;
        smS[row][1] = rsqrtf(var + 1e-6f);
    }
    __syncthreads();
    {
        int row = tid >> 3, j = tid & 7;
        int n = nb + row;
        if (n < N) {
            float mu = smS[row][0], rstd = smS[row][1];
#pragma unroll
            for (int c = j * 16; c < j * 16 + 16; ++c) {
                float y = g2[c] * (smDT[row * 132 + c] - mu) * rstd + be2[c];
                out[(size_t)n * 128 + c] = y;   // f32 output
            }
        }
    }
}

static inline size_t align256(size_t x) { return (x + 255) & ~(size_t)255; }

extern "C" void kernel_launch(void* const* d_in, const int* in_sizes, int n_in,
                              void* d_out, int out_size, void* d_ws, size_t ws_size,
                              hipStream_t stream) {
    const float* hV  = (const float*)d_in[0];
    const float* hE  = (const float*)d_in[1];
    const float* w1  = (const float*)d_in[2];
    const float* b1  = (const float*)d_in[3];
    const float* w2  = (const float*)d_in[4];
    const float* b2  = (const float*)d_in[5];
    const float* w3  = (const float*)d_in[6];
    const float* b3  = (const float*)d_in[7];
    const float* Av  = (const float*)d_in[8];
    const float* wi  = (const float*)d_in[9];
    const float* bi  = (const float*)d_in[10];
    const float* wo  = (const float*)d_in[11];
    const float* bo  = (const float*)d_in[12];
    const float* g1  = (const float*)d_in[13];
    const float* be1 = (const float*)d_in[14];
    const float* g2  = (const float*)d_in[15];
    const float* be2 = (const float*)d_in[16];
    const int* eidx  = (const int*)d_in[17];

    const int N = in_sizes[0] / 128;
    const int E = in_sizes[1] / 128;

    char* ws = (char*)d_ws;
    // w1t + w2t + w3t + wit + wot + w1a (shorts)
    const size_t wbytes = (size_t)(32768 + 16384 + 16384 + 65536 + 65536 + 4096) * 2;

    // ---- CSR-path layout ----
    size_t o_msg  = 0;                                     // E*128 bf16
    size_t o_att  = align256(o_msg + (size_t)E * 128 * 2); // E f32
    size_t o_eid  = align256(o_att + (size_t)E * 4);       // E i32
    size_t o_rp   = align256(o_eid + (size_t)E * 4);       // (N+1) i32
    size_t o_cnt  = align256(o_rp + (size_t)(N + 1) * 4);  // N i32 (cnt)
    size_t o_cur  = o_cnt + (size_t)N * 4;                 // N i32 (cursor)
    size_t o_hv1b = align256(o_cur + (size_t)N * 4);       // N*128 bf16
    size_t o_w    = align256(o_hv1b + (size_t)N * 128 * 2);
    size_t needed = o_w + wbytes;

    if (ws_size >= needed) {
        short* msg   = (short*)(ws + o_msg);
        float* att   = (float*)(ws + o_att);
        int*   eid   = (int*)(ws + o_eid);
        int*   rowp  = (int*)(ws + o_rp);
        int*   cnt   = (int*)(ws + o_cnt);
        int*   cur   = (int*)(ws + o_cur);
        short* hv1b  = (short*)(ws + o_hv1b);
        short* w1t   = (short*)(ws + o_w);
        short* w2t   = w1t + 32768;
        short* w3t   = w2t + 16384;
        short* wit   = w3t + 16384;
        short* wot   = wit + 65536;
        short* w1a   = wot + 65536;

        hipMemsetAsync(ws + o_cnt, 0, (size_t)2 * N * 4, stream);  // cnt + cursor
        prep_kernel<<<256, 256, 0, stream>>>(w1, w2, w3, wi, wo, Av,
                                             w1t, w2t, w3t, wit, wot, w1a);
        csr_count_kernel<<<(E + 255) / 256, 256, 0, stream>>>(eidx, E, cnt);
        csr_scan_kernel<<<1, 1024, 0, stream>>>(cnt, N, rowp);
        csr_scatter_kernel<<<(E + 255) / 256, 256, 0, stream>>>(eidx, E, rowp, cur, eid);
        edge_kernel<1><<<(E + 63) / 64, 512, 0, stream>>>(hV, hE, eidx, E, w1t, w2t, w3t,
                                                          w1a, b1, b2, b3,
                                                          nullptr, nullptr, msg, att);
        node1_csr_kernel<<<(N + 3) / 4, 256, 0, stream>>>(hV, msg, att, rowp, eid,
                                                          g1, be1, N, hv1b);
        ffn_kernel<<<(N + 31) / 32, 256, 0, stream>>>(hv1b, wit, wot, bi, bo, g2, be2,
                                                      N, (float*)d_out);
    } else {
        // ---- atomic fallback ----
        size_t f_num  = 0;                                              // N*128 f32
        size_t f_den  = f_num + (size_t)N * 128 * 4;                    // N f32
        size_t f_hv1b = align256(f_den + (size_t)N * 4);                // N*128 bf16
        size_t f_w    = align256(f_hv1b + (size_t)N * 128 * 2);

        float* num   = (float*)(ws + f_num);
        float* den   = (float*)(ws + f_den);
        short* hv1b  = (short*)(ws + f_hv1b);
        short* w1t   = (short*)(ws + f_w);
        short* w2t   = w1t + 32768;
        short* w3t   = w2t + 16384;
        short* wit   = w3t + 16384;
        short* wot   = wit + 65536;
        short* w1a   = wot + 65536;

        hipMemsetAsync(ws, 0, f_den + (size_t)N * 4, stream);
        prep_kernel<<<256, 256, 0, stream>>>(w1, w2, w3, wi, wo, Av,
                                             w1t, w2t, w3t, wit, wot, w1a);
        edge_kernel<0><<<(E + 63) / 64, 512, 0, stream>>>(hV, hE, eidx, E, w1t, w2t, w3t,
                                                          w1a, b1, b2, b3,
                                                          num, den, nullptr, nullptr);
        node1_kernel<<<(N + 3) / 4, 256, 0, stream>>>(hV, num, den, g1, be1, N, hv1b);
        ffn_kernel<<<(N + 31) / 32, 256, 0, stream>>>(hv1b, wit, wot, bi, bo, g2, be2,
                                                      N, (float*)d_out);
    }
}